// Round 12
// baseline (113.874 us; speedup 1.0000x reference)
//
#include <hip/hip_runtime.h>
#include <hip/hip_fp16.h>

// Problem constants
#define BB 512      // batch
#define FF 1024     // features (= K of GEMM, = NK*KD)
#define NK 64       // num kernels
#define KD 16       // kernel dim

#define REP 8       // R12 DECOMPOSITION PROBE: 8x in-kernel work repeat

typedef __attribute__((ext_vector_type(4))) float f32x4;
typedef __attribute__((ext_vector_type(8))) _Float16 half8;
typedef __attribute__((ext_vector_type(8))) unsigned short ushort8;

__device__ __forceinline__ unsigned short f16_bits(float f) {
    __half h = __float2half(f);   // RNE
    return *reinterpret_cast<unsigned short*>(&h);
}

// ---------------------------------------------------------------------------
// FUSED prep+GEMM (R10-verified) x REP passes (probe).
// ---------------------------------------------------------------------------
__global__ __launch_bounds__(256) void md_mfma_fused_kernel(
    const float* __restrict__ x, const float* __restrict__ T,
    float* __restrict__ M2, float* __restrict__ out) {
    __shared__ __align__(16) unsigned short lds[2][4096];

    const int t = threadIdx.x, w = t >> 6, l = t & 63;
    const int b = blockIdx.x, xc = b & 7, r = b >> 3;
    const int nt = xc * 4 + (r & 3);           // 0..31 (32-col n-tile)
    const int mt = r >> 2;                     // 0..15 (32-row m-tile)

    // zero `out` (128 KB) by blocks 0..3 (pairwise atomicAdds on top)
    if (b < 4) {
        const float4 z = make_float4(0.f, 0.f, 0.f, 0.f);
        #pragma unroll
        for (int q = 0; q < 8; ++q)
            *(float4*)&out[(size_t)(b * 2048 + q * 256 + t) * 4] = z;
    }

    const int rowA = t >> 3, k8 = t & 7;
    const float* gA = x + (size_t)(mt * 32 + rowA) * FF + k8 * 8;
    const int wA = rowA * 64 + ((k8 ^ (rowA & 7)) * 8);   // swizzled ushort idx

    const int k2 = (t >> 3) * 2, nB = (t & 7) * 4;
    const float* gB = T + (size_t)k2 * FF + nt * 32 + nB;
    const int c16B = ((k2 >> 3) * 8);

    const int lrow = l & 15, lkg = l >> 4;
    const int ar = (w >> 1) * 16 + lrow;       // A row 0..31
    const int br = (w & 1) * 16 + lrow;        // B row 0..31
    const int swa = ar & 7, swb = br & 7;

    float4 a0[2], a1[2], b0[2], b1[2];

#define LOADT(s, it_) do {                                                  \
        a0[s] = *(const float4*)(gA + (it_) * 64);                          \
        a1[s] = *(const float4*)(gA + (it_) * 64 + 4);                      \
        b0[s] = *(const float4*)(gB + (size_t)(it_) * 64 * FF);             \
        b1[s] = *(const float4*)(gB + (size_t)(it_) * 64 * FF + FF);        \
    } while (0)

#define CVTW(s, bf) do {                                                    \
        ushort8 hv;                                                         \
        hv[0] = f16_bits(a0[s].x); hv[1] = f16_bits(a0[s].y);               \
        hv[2] = f16_bits(a0[s].z); hv[3] = f16_bits(a0[s].w);               \
        hv[4] = f16_bits(a1[s].x); hv[5] = f16_bits(a1[s].y);               \
        hv[6] = f16_bits(a1[s].z); hv[7] = f16_bits(a1[s].w);               \
        *(ushort8*)&lds[bf][wA] = hv;                                       \
        const float q0[4] = {b0[s].x, b0[s].y, b0[s].z, b0[s].w};           \
        const float q1[4] = {b1[s].x, b1[s].y, b1[s].z, b1[s].w};           \
        _Pragma("unroll")                                                   \
        for (int j = 0; j < 4; ++j) {                                       \
            const unsigned int pk = (unsigned int)f16_bits(q0[j]) |         \
                                    ((unsigned int)f16_bits(q1[j]) << 16);  \
            const int n = nB + j;                                           \
            *(unsigned int*)&lds[bf][2048 + n * 64 +                        \
                (c16B ^ ((n & 7) * 8)) + (k2 & 7)] = pk;                    \
        }                                                                   \
    } while (0)

    #pragma unroll 1
    for (int pass = 0; pass < REP; ++pass) {
        __syncthreads();               // protect LDS reuse across passes
        f32x4 acc = {};

        LOADT(0, 0);
        LOADT(1, 1);
        CVTW(0, 0);
        __syncthreads();

        #pragma unroll
        for (int it = 0; it < 16; ++it) {
            const int s = it & 1;
            if (it + 2 < 16) LOADT(s, it + 2);
            const unsigned short* L = lds[s];
            #pragma unroll
            for (int ks = 0; ks < 2; ++ks) {
                const int cb = ks * 4 + lkg;
                const half8 af = *(const half8*)&L[ar * 64 + ((cb ^ swa) * 8)];
                const half8 bf = *(const half8*)&L[2048 + br * 64 + ((cb ^ swb) * 8)];
                acc = __builtin_amdgcn_mfma_f32_16x16x32_f16(af, bf, acc, 0, 0, 0);
            }
            if (it + 1 < 16) {
                CVTW(s ^ 1, s ^ 1);
                __syncthreads();
            }
        }

        // C/D (m89): col = lane&15, row = (lane>>4)*4 + reg
        const int kblk = nt * 2 + (w & 1);           // 0..63
        const int rowb = mt * 32 + (w >> 1) * 16 + lkg * 4;
        #pragma unroll
        for (int rg = 0; rg < 4; ++rg)
            M2[((size_t)kblk * BB + rowb + rg) * KD + lrow] = acc[rg];
    }
#undef LOADT
#undef CVTW
}

// ---------------------------------------------------------------------------
// Symmetric pairwise (R10-verified) x REP passes (probe); atomics last pass.
// ---------------------------------------------------------------------------
__global__ __launch_bounds__(256) void md_pairwise_sym_kernel(
    const float* __restrict__ M2, float* __restrict__ out) {
    __shared__ float Mj[64][16];
    __shared__ float et[64][65];
    __shared__ float part_row[4][64];
    __shared__ float part_col[4][64];

    const int bx = blockIdx.x;
    const int k = bx & 63;
    int p = bx >> 6;
    int it = 0;
    while (p >= 8 - it) { p -= 8 - it; ++it; }
    const int jt = it + p;
    const bool diag = (it == jt);
    const int t = threadIdx.x;

    const float* tileI = M2 + ((size_t)k * BB + it * 64) * KD;
    const float* tileJ = M2 + ((size_t)k * BB + jt * 64) * KD;

    const int i = t & 63;
    const int wv = t >> 6;

    // mi once (registers persist across passes)
    float mi[16];
    #pragma unroll
    for (int dg = 0; dg < 4; ++dg) {
        const float4 v = *(const float4*)&tileI[i * KD + dg * 4];
        mi[dg * 4 + 0] = v.x; mi[dg * 4 + 1] = v.y;
        mi[dg * 4 + 2] = v.z; mi[dg * 4 + 3] = v.w;
    }

    #pragma unroll 1
    for (int pass = 0; pass < REP; ++pass) {
        __syncthreads();               // protect Mj/et/part reuse across passes
        {
            const int row = t >> 2, dg = (t & 3) * 4;
            *(float4*)&Mj[row][dg] = *(const float4*)&tileJ[t * 4];
        }
        __syncthreads();

        float row_acc = 0.0f;
        #pragma unroll 4
        for (int jj = 0; jj < 16; ++jj) {
            const int j = wv * 16 + jj;      // wave-uniform -> broadcast reads
            const float4* mj = (const float4*)&Mj[j][0];
            const float4 v0 = mj[0], v1 = mj[1], v2 = mj[2], v3 = mj[3];
            float p0 = (fabsf(mi[0] - v0.x) + fabsf(mi[1] - v0.y)) +
                       (fabsf(mi[2] - v0.z) + fabsf(mi[3] - v0.w));
            float p1 = (fabsf(mi[4] - v1.x) + fabsf(mi[5] - v1.y)) +
                       (fabsf(mi[6] - v1.z) + fabsf(mi[7] - v1.w));
            float p2 = (fabsf(mi[8] - v2.x) + fabsf(mi[9] - v2.y)) +
                       (fabsf(mi[10] - v2.z) + fabsf(mi[11] - v2.w));
            float p3 = (fabsf(mi[12] - v3.x) + fabsf(mi[13] - v3.y)) +
                       (fabsf(mi[14] - v3.z) + fabsf(mi[15] - v3.w));
            const float e = __expf(-((p0 + p1) + (p2 + p3)));
            row_acc += e;
            et[i][j] = e;                    // banks (i+j)%32 -> conflict-free
        }
        part_row[wv][i] = row_acc;
        __syncthreads();

        if (!diag) {
            const int j = t & 63;
            const int chunk = t >> 6;
            float col_acc = 0.0f;
            #pragma unroll
            for (int ii = 0; ii < 16; ++ii)
                col_acc += et[chunk * 16 + ii][j];
            part_col[chunk][j] = col_acc;
        }
        __syncthreads();

        if (pass == REP - 1) {               // output only on last pass
            if (t < 64) {
                float rr = ((part_row[0][t] + part_row[1][t]) +
                            (part_row[2][t] + part_row[3][t])) - (diag ? 1.0f : 0.0f);
                atomicAdd(&out[(size_t)(it * 64 + t) * NK + k], rr);
            } else if (t < 128 && !diag) {
                const int j = t - 64;
                float c = (part_col[0][j] + part_col[1][j]) +
                          (part_col[2][j] + part_col[3][j]);
                atomicAdd(&out[(size_t)(jt * 64 + j) * NK + k], c);
            }
        }
    }
}

extern "C" void kernel_launch(void* const* d_in, const int* in_sizes, int n_in,
                              void* d_out, int out_size, void* d_ws, size_t ws_size,
                              hipStream_t stream) {
    const float* x = (const float*)d_in[0];   // [512, 1024] f32
    const float* T = (const float*)d_in[1];   // [1024, 1024] f32
    float* out = (float*)d_out;               // [512, 64] f32

    float* M2 = (float*)d_ws;                 // [64][512][16] f32 (2 MB)

    md_mfma_fused_kernel<<<dim3(512), 256, 0, stream>>>(x, T, M2, out);
    md_pairwise_sym_kernel<<<dim3(36 * 64), 256, 0, stream>>>(M2, out);
}

// Round 13
// 29.074 us; speedup vs baseline: 3.9166x; 3.9166x over previous
//
#include <hip/hip_runtime.h>
#include <hip/hip_fp16.h>

// Problem constants
#define BB 512      // batch
#define FF 1024     // features (= K of GEMM, = NK*KD)
#define NK 64       // num kernels
#define KD 16       // kernel dim

typedef __attribute__((ext_vector_type(4))) float f32x4;
typedef __attribute__((ext_vector_type(8))) _Float16 half8;
typedef __attribute__((ext_vector_type(8))) unsigned short ushort8;

__device__ __forceinline__ unsigned short f16_bits(float f) {
    __half h = __float2half(f);   // RNE
    return *reinterpret_cast<unsigned short*>(&h);
}

// ---------------------------------------------------------------------------
// FUSED prep+GEMM (R10-verified): f32 x,T -> in-reg f16 -> swizzled LDS ->
// MFMA. BM=32,BN=32,BK=64; 512 blocks, 256 thr, dbuf. Blocks 0..3 zero out.
// Output M2[kblk][512][16] f32; kblk produced on XCD kblk>>3.
// ---------------------------------------------------------------------------
__global__ __launch_bounds__(256) void md_mfma_fused_kernel(
    const float* __restrict__ x, const float* __restrict__ T,
    float* __restrict__ M2, float* __restrict__ out) {
    __shared__ __align__(16) unsigned short lds[2][4096];

    const int t = threadIdx.x, w = t >> 6, l = t & 63;
    const int b = blockIdx.x, xc = b & 7, r = b >> 3;
    const int nt = xc * 4 + (r & 3);           // 0..31 (32-col n-tile)
    const int mt = r >> 2;                     // 0..15 (32-row m-tile)

    if (b < 4) {
        const float4 z = make_float4(0.f, 0.f, 0.f, 0.f);
        #pragma unroll
        for (int q = 0; q < 8; ++q)
            *(float4*)&out[(size_t)(b * 2048 + q * 256 + t) * 4] = z;
    }

    const int rowA = t >> 3, k8 = t & 7;
    const float* gA = x + (size_t)(mt * 32 + rowA) * FF + k8 * 8;
    const int wA = rowA * 64 + ((k8 ^ (rowA & 7)) * 8);   // swizzled ushort idx

    const int k2 = (t >> 3) * 2, nB = (t & 7) * 4;
    const float* gB = T + (size_t)k2 * FF + nt * 32 + nB;
    const int c16B = ((k2 >> 3) * 8);

    const int lrow = l & 15, lkg = l >> 4;
    const int ar = (w >> 1) * 16 + lrow;       // A row 0..31
    const int br = (w & 1) * 16 + lrow;        // B row 0..31
    const int swa = ar & 7, swb = br & 7;

    f32x4 acc = {};
    float4 a0[2], a1[2], b0[2], b1[2];

#define LOADT(s, it_) do {                                                  \
        a0[s] = *(const float4*)(gA + (it_) * 64);                          \
        a1[s] = *(const float4*)(gA + (it_) * 64 + 4);                      \
        b0[s] = *(const float4*)(gB + (size_t)(it_) * 64 * FF);             \
        b1[s] = *(const float4*)(gB + (size_t)(it_) * 64 * FF + FF);        \
    } while (0)

#define CVTW(s, bf) do {                                                    \
        ushort8 hv;                                                         \
        hv[0] = f16_bits(a0[s].x); hv[1] = f16_bits(a0[s].y);               \
        hv[2] = f16_bits(a0[s].z); hv[3] = f16_bits(a0[s].w);               \
        hv[4] = f16_bits(a1[s].x); hv[5] = f16_bits(a1[s].y);               \
        hv[6] = f16_bits(a1[s].z); hv[7] = f16_bits(a1[s].w);               \
        *(ushort8*)&lds[bf][wA] = hv;                                       \
        const float q0[4] = {b0[s].x, b0[s].y, b0[s].z, b0[s].w};           \
        const float q1[4] = {b1[s].x, b1[s].y, b1[s].z, b1[s].w};           \
        _Pragma("unroll")                                                   \
        for (int j = 0; j < 4; ++j) {                                       \
            const unsigned int pk = (unsigned int)f16_bits(q0[j]) |         \
                                    ((unsigned int)f16_bits(q1[j]) << 16);  \
            const int n = nB + j;                                           \
            *(unsigned int*)&lds[bf][2048 + n * 64 +                        \
                (c16B ^ ((n & 7) * 8)) + (k2 & 7)] = pk;                    \
        }                                                                   \
    } while (0)

    LOADT(0, 0);
    LOADT(1, 1);
    CVTW(0, 0);
    __syncthreads();

    #pragma unroll
    for (int it = 0; it < 16; ++it) {
        const int s = it & 1;
        if (it + 2 < 16) LOADT(s, it + 2);
        const unsigned short* L = lds[s];
        #pragma unroll
        for (int ks = 0; ks < 2; ++ks) {
            const int cb = ks * 4 + lkg;
            const half8 af = *(const half8*)&L[ar * 64 + ((cb ^ swa) * 8)];
            const half8 bf = *(const half8*)&L[2048 + br * 64 + ((cb ^ swb) * 8)];
            acc = __builtin_amdgcn_mfma_f32_16x16x32_f16(af, bf, acc, 0, 0, 0);
        }
        if (it + 1 < 16) {
            CVTW(s ^ 1, s ^ 1);
            __syncthreads();
        }
    }
#undef LOADT
#undef CVTW

    const int kblk = nt * 2 + (w & 1);           // 0..63
    const int rowb = mt * 32 + (w >> 1) * 16 + lkg * 4;
    #pragma unroll
    for (int rg = 0; rg < 4; ++rg)
        M2[((size_t)kblk * BB + rowb + rg) * KD + lrow] = acc[rg];
}

// ---------------------------------------------------------------------------
// Symmetric pairwise v3: mj via wave-uniform SCALAR loads from global
// (L2-hot, k XCD-matched to GEMM producer) — the Mj LDS tile and its 64
// broadcast ds_read_b128/wave (the measured 11-us DS-pipe bottleneck) are
// deleted. et tile + col pass + atomics unchanged from R10 (verified).
// 2304 blocks x 256 thr; k = ((bx&7)<<3)|((bx>>3)&7) keeps k's 32KB panel
// on the consuming XCD's L2.
// ---------------------------------------------------------------------------
__global__ __launch_bounds__(256) void md_pairwise_sym_kernel(
    const float* __restrict__ M2, float* __restrict__ out) {
    __shared__ float et[64][65];
    __shared__ float part_row[4][64];
    __shared__ float part_col[4][64];

    const int bx = blockIdx.x;
    const int k = ((bx & 7) << 3) | ((bx >> 3) & 7);   // XCD-local k
    int p = bx >> 6;
    int it = 0;
    while (p >= 8 - it) { p -= 8 - it; ++it; }
    const int jt = it + p;
    const bool diag = (it == jt);
    const int t = threadIdx.x;

    const float* tileI = M2 + ((size_t)k * BB + it * 64) * KD;
    const float* tileJ = M2 + ((size_t)k * BB + jt * 64) * KD;

    const int i = t & 63;
    const int wv = t >> 6;

    // mi: per-lane row, coalesced VMEM
    float mi[16];
    #pragma unroll
    for (int dg = 0; dg < 4; ++dg) {
        const float4 v = *(const float4*)&tileI[i * KD + dg * 4];
        mi[dg * 4 + 0] = v.x; mi[dg * 4 + 1] = v.y;
        mi[dg * 4 + 2] = v.z; mi[dg * 4 + 3] = v.w;
    }

    float row_acc = 0.0f;
    #pragma unroll 4
    for (int jj = 0; jj < 16; ++jj) {
        const int j = wv * 16 + jj;
        // wave-uniform offset -> scalar (s_load) path, zero DS
        const int off = __builtin_amdgcn_readfirstlane(j * KD);
        const float4 v0 = *(const float4*)(tileJ + off);
        const float4 v1 = *(const float4*)(tileJ + off + 4);
        const float4 v2 = *(const float4*)(tileJ + off + 8);
        const float4 v3 = *(const float4*)(tileJ + off + 12);
        float p0 = (fabsf(mi[0] - v0.x) + fabsf(mi[1] - v0.y)) +
                   (fabsf(mi[2] - v0.z) + fabsf(mi[3] - v0.w));
        float p1 = (fabsf(mi[4] - v1.x) + fabsf(mi[5] - v1.y)) +
                   (fabsf(mi[6] - v1.z) + fabsf(mi[7] - v1.w));
        float p2 = (fabsf(mi[8] - v2.x) + fabsf(mi[9] - v2.y)) +
                   (fabsf(mi[10] - v2.z) + fabsf(mi[11] - v2.w));
        float p3 = (fabsf(mi[12] - v3.x) + fabsf(mi[13] - v3.y)) +
                   (fabsf(mi[14] - v3.z) + fabsf(mi[15] - v3.w));
        const float e = __expf(-((p0 + p1) + (p2 + p3)));
        row_acc += e;
        et[i][j] = e;                    // banks (i+j)%32 -> conflict-free
    }
    part_row[wv][i] = row_acc;
    __syncthreads();

    if (!diag) {
        const int j = t & 63;
        const int chunk = t >> 6;
        float col_acc = 0.0f;
        #pragma unroll
        for (int ii = 0; ii < 16; ++ii)
            col_acc += et[chunk * 16 + ii][j];
        part_col[chunk][j] = col_acc;
    }
    __syncthreads();

    if (t < 64) {
        float r = ((part_row[0][t] + part_row[1][t]) +
                   (part_row[2][t] + part_row[3][t])) - (diag ? 1.0f : 0.0f);
        atomicAdd(&out[(size_t)(it * 64 + t) * NK + k], r);
    } else if (t < 128 && !diag) {
        const int j = t - 64;
        float c = (part_col[0][j] + part_col[1][j]) +
                  (part_col[2][j] + part_col[3][j]);
        atomicAdd(&out[(size_t)(jt * 64 + j) * NK + k], c);
    }
}

extern "C" void kernel_launch(void* const* d_in, const int* in_sizes, int n_in,
                              void* d_out, int out_size, void* d_ws, size_t ws_size,
                              hipStream_t stream) {
    const float* x = (const float*)d_in[0];   // [512, 1024] f32
    const float* T = (const float*)d_in[1];   // [1024, 1024] f32
    float* out = (float*)d_out;               // [512, 64] f32

    float* M2 = (float*)d_ws;                 // [64][512][16] f32 (2 MB)

    md_mfma_fused_kernel<<<dim3(512), 256, 0, stream>>>(x, T, M2, out);
    md_pairwise_sym_kernel<<<dim3(36 * 64), 256, 0, stream>>>(M2, out);
}